// Round 17
// baseline (4425.857 us; speedup 1.0000x reference)
//
#include <hip/hip_runtime.h>
#include <cstdint>
#include <cstddef>

#define B_   64
#define S_   49
#define T_   32
#define D_   512
#define V_   32000
#define G3   1536

typedef float v4f   __attribute__((ext_vector_type(4)));
typedef int   i32x4 __attribute__((ext_vector_type(4)));
typedef _Float16 f16;
typedef _Float16 f16x8 __attribute__((ext_vector_type(8)));
typedef _Float16 f16x4 __attribute__((ext_vector_type(4)));
typedef _Float16 f16x2 __attribute__((ext_vector_type(2)));

__device__ __forceinline__ float sigm(float x) { return 1.f / (1.f + __expf(-x)); }

// dot of 8 f16 pairs accumulated into fp32
__device__ __forceinline__ float dot8(f16x8 a, f16x8 b, float acc) {
#if __has_builtin(__builtin_amdgcn_fdot2)
  f16x2 a0 = {a[0], a[1]}, b0 = {b[0], b[1]};
  f16x2 a1 = {a[2], a[3]}, b1 = {b[2], b[3]};
  f16x2 a2 = {a[4], a[5]}, b2 = {b[4], b[5]};
  f16x2 a3 = {a[6], a[7]}, b3 = {b[6], b[7]};
  acc = __builtin_amdgcn_fdot2(a0, b0, acc, false);
  acc = __builtin_amdgcn_fdot2(a1, b1, acc, false);
  acc = __builtin_amdgcn_fdot2(a2, b2, acc, false);
  acc = __builtin_amdgcn_fdot2(a3, b3, acc, false);
#else
  #pragma unroll
  for (int i = 0; i < 8; ++i) acc = fmaf((float)a[i], (float)b[i], acc);
#endif
  return acc;
}

__device__ __forceinline__ void cvt8(const float* __restrict__ in,
                                     f16* __restrict__ out) {
  float4 a = *(const float4*)in;
  float4 b = *(const float4*)(in + 4);
  f16x8 o;
  o[0] = (f16)a.x; o[1] = (f16)a.y; o[2] = (f16)a.z; o[3] = (f16)a.w;
  o[4] = (f16)b.x; o[5] = (f16)b.y; o[6] = (f16)b.z; o[7] = (f16)b.w;
  *(f16x8*)out = o;
}

// ---------------- merged prep kernel: all elementwise/convert/pack work ----------------
__global__ __launch_bounds__(256) void k_prep(
    const float* __restrict__ Wout, f16* __restrict__ Woutb,
    const float* __restrict__ Wea, f16* __restrict__ Wea16,
    const float* __restrict__ feats, f16* __restrict__ feats16,
    const float* __restrict__ emb, const int* __restrict__ seq,
    const int* __restrict__ length,
    f16* __restrict__ xemb16, float* __restrict__ actmask,
    float* __restrict__ hmean,
    const float* __restrict__ Wda, const float* __restrict__ Wbe,
    const float* __restrict__ Whh, const float* __restrict__ Wih,
    f16* __restrict__ Wfull1, f16* __restrict__ Wfull2,
    f16* __restrict__ Wp3) {
  const size_t N1 = (size_t)V_ * D_ / 8;
  const size_t N2 = N1 + (size_t)D_ * D_ / 8;
  const size_t N3 = N2 + (size_t)B_ * S_ * D_ / 8;
  const size_t N4 = N3 + (size_t)B_ * T_ * D_ / 8;
  const size_t N5 = N4 + (size_t)B_ * D_;
  const size_t N6 = N5 + (size_t)B_ * T_;
  const size_t N7 = N6 + (size_t)2560 * 64;
  const size_t N8 = N7 + (size_t)G3 * 64;
  const size_t N9 = N8 + (size_t)G3 * 64;
  for (size_t i = (size_t)blockIdx.x * 256 + threadIdx.x; i < N9;
       i += (size_t)gridDim.x * 256) {
    if (i < N1) {
      cvt8(Wout + i * 8, Woutb + i * 8);
    } else if (i < N2) {
      size_t j = i - N1;
      cvt8(Wea + j * 8, Wea16 + j * 8);
    } else if (i < N3) {
      size_t j = i - N2;
      cvt8(feats + j * 8, feats16 + j * 8);
    } else if (i < N4) {
      size_t j = i - N3;
      int m = (int)(j >> 6), c = (int)(j & 63);
      int t = m >> 6, b = m & 63;
      int idx = seq[b * T_ + t];
      cvt8(emb + (size_t)idx * D_ + c * 8, xemb16 + (size_t)m * D_ + c * 8);
    } else if (i < N5) {
      size_t j = i - N4;
      int b = (int)(j >> 9), e = (int)(j & 511);
      float s = 0.f;
      for (int si = 0; si < S_; ++si)
        s += feats[((size_t)b * S_ + si) * D_ + e];
      hmean[b * D_ + e] = s * (1.f / 49.f);
    } else if (i < N6) {
      size_t j = i - N5;
      int b = (int)(j >> 5), t = (int)(j & 31);
      actmask[b * T_ + t] = (t < length[b]) ? 1.f : 0.f;
    } else if (i < N7) {
      size_t j = i - N6;
      int row = (int)(j >> 6), e8 = (int)(j & 63);
      const float* src;
      if (row < 512)       src = Wda + (size_t)row * D_ + e8 * 8;
      else if (row < 1024) src = Wbe + (size_t)(row - 512) * D_ + e8 * 8;
      else                 src = Whh + (size_t)(row - 1024) * D_ + e8 * 8;
      cvt8(src, Wfull1 + (size_t)row * D_ + e8 * 8);
    } else if (i < N8) {
      size_t j = i - N7;
      int q = (int)(j >> 6), e8 = (int)(j & 63);
      cvt8(Wih + (size_t)q * 1024 + 512 + e8 * 8, Wfull2 + (size_t)q * D_ + e8 * 8);
    } else {
      size_t j = i - N8;
      int q = (int)(j >> 6), e8 = (int)(j & 63);
      cvt8(Wih + (size_t)q * 1024 + e8 * 8, Wp3 + (size_t)q * D_ + e8 * 8);
    }
  }
}

// ---------------- fp32 GEMM (h0 only): also emits f16 copy ----------------
__global__ __launch_bounds__(256) void k_gemm_f32(
    float* __restrict__ C, f16* __restrict__ C16,
    const float* __restrict__ X, const float* __restrict__ W,
    const float* __restrict__ bias, int N, int K, int ldw) {
  __shared__ __align__(16) float XsT[32][68];
  __shared__ __align__(16) float WsT[32][68];
  const int nbase = blockIdx.x * 64, mbase = blockIdx.y * 64;
  const int tid = threadIdx.x;
  const int lr = tid >> 2;
  const int lk = (tid & 3) * 8;
  const int ty = tid >> 4, tx = tid & 15;
  float acc[4][4] = {};
  for (int k0 = 0; k0 < K; k0 += 32) {
    {
      const float* xs = X + (size_t)(mbase + lr) * K + k0 + lk;
      const float* wsrc = W + (size_t)(nbase + lr) * ldw + k0 + lk;
      float4 x0 = *(const float4*)xs, x1 = *(const float4*)(xs + 4);
      float4 w0 = *(const float4*)wsrc, w1 = *(const float4*)(wsrc + 4);
      XsT[lk + 0][lr] = x0.x; XsT[lk + 1][lr] = x0.y; XsT[lk + 2][lr] = x0.z; XsT[lk + 3][lr] = x0.w;
      XsT[lk + 4][lr] = x1.x; XsT[lk + 5][lr] = x1.y; XsT[lk + 6][lr] = x1.z; XsT[lk + 7][lr] = x1.w;
      WsT[lk + 0][lr] = w0.x; WsT[lk + 1][lr] = w0.y; WsT[lk + 2][lr] = w0.z; WsT[lk + 3][lr] = w0.w;
      WsT[lk + 4][lr] = w1.x; WsT[lk + 5][lr] = w1.y; WsT[lk + 6][lr] = w1.z; WsT[lk + 7][lr] = w1.w;
    }
    __syncthreads();
    #pragma unroll
    for (int kk = 0; kk < 32; ++kk) {
      float4 a4 = *(const float4*)&XsT[kk][ty * 4];
      float4 w4 = *(const float4*)&WsT[kk][tx * 4];
      float av[4] = {a4.x, a4.y, a4.z, a4.w};
      float wv[4] = {w4.x, w4.y, w4.z, w4.w};
      #pragma unroll
      for (int i = 0; i < 4; ++i)
        #pragma unroll
        for (int j = 0; j < 4; ++j)
          acc[i][j] = fmaf(av[i], wv[j], acc[i][j]);
    }
    __syncthreads();
  }
  #pragma unroll
  for (int i = 0; i < 4; ++i) {
    int m = mbase + ty * 4 + i;
    int n = nbase + tx * 4;
    float4 o;
    o.x = acc[i][0] + bias[n + 0];
    o.y = acc[i][1] + bias[n + 1];
    o.z = acc[i][2] + bias[n + 2];
    o.w = acc[i][3] + bias[n + 3];
    *(float4*)&C[(size_t)m * N + n] = o;
    if (C16) {
      f16x4 h;
      h[0] = (f16)o.x; h[1] = (f16)o.y; h[2] = (f16)o.z; h[3] = (f16)o.w;
      *(f16x4*)&C16[(size_t)m * N + n] = h;
    }
  }
}

// ---------------- f16 MFMA GEMM core ----------------
#define GEMM16_CORE                                                            \
  __shared__ __align__(16) f16 As[128 * 32];                                   \
  __shared__ __align__(16) f16 Bs[128 * 32];                                   \
  const int tid = threadIdx.x;                                                 \
  const int l = tid & 63, w = tid >> 6;                                        \
  const int wr = w >> 1, wc = w & 1;                                           \
  const int lm = l & 15;                                                       \
  const int kc = l >> 4;                                                       \
  const int rchunk = (kc ^ ((lm >> 1) & 3)) * 8;                               \
  v4f acc[4][4];                                                               \
  _Pragma("unroll")                                                            \
  for (int mi = 0; mi < 4; ++mi)                                               \
    _Pragma("unroll")                                                          \
    for (int ni = 0; ni < 4; ++ni)                                             \
      acc[mi][ni] = (v4f){0.f, 0.f, 0.f, 0.f};                                 \
  i32x4 ra[2], rb[2];                                                          \
  auto LD = [&](int k0) {                                                      \
    _Pragma("unroll")                                                          \
    for (int i = 0; i < 2; ++i) {                                              \
      int ch = i * 256 + tid;                                                  \
      int row = ch >> 2, cq = ch & 3;                                          \
      ra[i] = *(const i32x4*)&A[(size_t)(mb + row) * 512 + k0 + cq * 8];       \
      rb[i] = *(const i32x4*)&Bw[(size_t)(nb + row) * 512 + k0 + cq * 8];      \
    }                                                                          \
  };                                                                           \
  LD(0);                                                                       \
  for (int k0 = 0; k0 < 512; k0 += 32) {                                       \
    _Pragma("unroll")                                                          \
    for (int i = 0; i < 2; ++i) {                                              \
      int ch = i * 256 + tid;                                                  \
      int row = ch >> 2, cq = ch & 3;                                          \
      int sc = (cq ^ ((row >> 1) & 3)) * 8;                                    \
      *(i32x4*)&As[row * 32 + sc] = ra[i];                                     \
      *(i32x4*)&Bs[row * 32 + sc] = rb[i];                                     \
    }                                                                          \
    __syncthreads();                                                           \
    if (k0 < 480) LD(k0 + 32);                                                 \
    f16x8 af[4], bf[4];                                                        \
    _Pragma("unroll")                                                          \
    for (int mi = 0; mi < 4; ++mi)                                             \
      af[mi] = *(const f16x8*)&As[(wr * 64 + mi * 16 + lm) * 32 + rchunk];     \
    _Pragma("unroll")                                                          \
    for (int ni = 0; ni < 4; ++ni)                                             \
      bf[ni] = *(const f16x8*)&Bs[(wc * 64 + ni * 16 + lm) * 32 + rchunk];     \
    _Pragma("unroll")                                                          \
    for (int mi = 0; mi < 4; ++mi)                                             \
      _Pragma("unroll")                                                        \
      for (int ni = 0; ni < 4; ++ni)                                           \
        acc[mi][ni] = __builtin_amdgcn_mfma_f32_16x16x32_f16(af[mi], bf[ni], acc[mi][ni], 0, 0, 0); \
    __syncthreads();                                                           \
  }

// att116 = feats16 @ W_ea16.T + b_ea -> f16 out, M guarded at 3136
__global__ __launch_bounds__(256) void k_gemm16f(
    const f16* __restrict__ A, const f16* __restrict__ Bw,
    const float* __restrict__ bias, f16* __restrict__ out) {
  const int nb = blockIdx.x * 128, mb = blockIdx.y * 128;
  GEMM16_CORE
  #pragma unroll
  for (int ni = 0; ni < 4; ++ni) {
    int n = nb + wc * 64 + ni * 16 + lm;
    float bo = bias[n];
    #pragma unroll
    for (int mi = 0; mi < 4; ++mi) {
      int m0 = mb + wr * 64 + mi * 16 + (l >> 4) * 4;
      #pragma unroll
      for (int r = 0; r < 4; ++r) {
        int m = m0 + r;
        if (m < B_ * S_) out[(size_t)m * 512 + n] = (f16)(acc[mi][ni][r] + bo);
      }
    }
  }
}

// gi = xemb16 @ Wp3.T + b_ih, plain fp32 [2048][1536]
__global__ __launch_bounds__(256) void k_gemm16g(
    const f16* __restrict__ A, const f16* __restrict__ Bw,
    const float* __restrict__ bias, float* __restrict__ out) {
  const int nb = blockIdx.x * 128, mb = blockIdx.y * 128;
  GEMM16_CORE
  #pragma unroll
  for (int ni = 0; ni < 4; ++ni) {
    int n = nb + wc * 64 + ni * 16 + lm;
    float bo = bias[n];
    #pragma unroll
    for (int mi = 0; mi < 4; ++mi) {
      int m0 = mb + wr * 64 + mi * 16 + (l >> 4) * 4;
      #pragma unroll
      for (int r = 0; r < 4; ++r)
        out[(size_t)(m0 + r) * G3 + n] = acc[mi][ni][r] + bo;
    }
  }
}

// ---------------- R16fix: batch-parallel ZERO-SYNC recurrence ----------------
// 64 blocks, block b owns batch b for all 32 steps. feats16[b]+att116[b] in
// LDS (100KB); step-invariant weights streamed from L2. No cross-block sync.
// FIX: prologue stages S_*64 uint4 chunks per tile (a 512-f16 row = 64 chunks,
// not 32 -- R16 staged only half, leaving poison in rows >= 25).
__global__ __launch_bounds__(256, 1) void k_recur(
    const f16* __restrict__ Wfull1, const f16* __restrict__ Wfull2,
    const f16* __restrict__ att116, const f16* __restrict__ feats16,
    const float* __restrict__ gi,
    const float* __restrict__ b_da, const float* __restrict__ b_beta,
    const float* __restrict__ b_hh,
    const float* __restrict__ W_fa, const float* __restrict__ b_fa,
    const int* __restrict__ length, const f16* __restrict__ h016,
    float* __restrict__ alphas, f16* __restrict__ Hbuf) {
  __shared__ __align__(16) f16 fe[S_ * 512];
  __shared__ __align__(16) f16 at[S_ * 512];
  __shared__ __align__(16) f16 hx[512];
  __shared__ __align__(16) f16 xg[512];
  __shared__ float att2_s[512];
  __shared__ float gate_s[512];
  __shared__ float gh[1536];
  __shared__ float gix[1536];
  __shared__ float att_s[64];
  __shared__ float alpha_s[64];

  const int b = blockIdx.x, tid = threadIdx.x;
  const int w = tid >> 6, l = tid & 63;

  // ---- prologue: stage per-batch inputs (S_*64 uint4 chunks each) ----
  {
    const uint4* fs = (const uint4*)(feats16 + (size_t)b * S_ * 512);
    const uint4* as = (const uint4*)(att116 + (size_t)b * S_ * 512);
    for (int i = tid; i < S_ * 64; i += 256) {
      ((uint4*)fe)[i] = fs[i];
      ((uint4*)at)[i] = as[i];
    }
    if (tid < 64) ((uint4*)hx)[tid] = ((const uint4*)(h016 + (size_t)b * 512))[tid];
  }
  const int lenB = length[b];
  const float bfa0 = b_fa[0];
  float wfa[8];
  {
    int a0i = l * 8;
    #pragma unroll
    for (int jx = 0; jx < 8; ++jx) wfa[jx] = W_fa[a0i + jx];
  }
  const float bda0 = b_da[tid], bda1 = b_da[256 + tid];
  const float bbe0 = b_beta[tid], bbe1 = b_beta[256 + tid];
  float bhh6[6];
  #pragma unroll
  for (int g = 0; g < 6; ++g) bhh6[g] = b_hh[g * 256 + tid];
  float scope_r = 1.f;
  __syncthreads();

  for (int t = 0; t < T_; ++t) {
    // ---- phase 1: rows of [Wda|Wbe|Whh_r|Whh_z|Whh_n] (2560) dot h ----
    {
      float acc1[10];
      #pragma unroll
      for (int g = 0; g < 10; ++g) acc1[g] = 0.f;
      #pragma unroll 1
      for (int kt = 0; kt < 16; ++kt) {
        f16x8 hv0 = *(const f16x8*)&hx[kt * 32];
        f16x8 hv1 = *(const f16x8*)&hx[kt * 32 + 8];
        f16x8 hv2 = *(const f16x8*)&hx[kt * 32 + 16];
        f16x8 hv3 = *(const f16x8*)&hx[kt * 32 + 24];
        #pragma unroll
        for (int g = 0; g < 10; ++g) {
          const f16* wr = Wfull1 + (size_t)(g * 256 + tid) * 512 + kt * 32;
          f16x8 w0 = *(const f16x8*)wr;
          f16x8 w1 = *(const f16x8*)(wr + 8);
          f16x8 w2 = *(const f16x8*)(wr + 16);
          f16x8 w3 = *(const f16x8*)(wr + 24);
          acc1[g] = dot8(hv3, w3, dot8(hv2, w2, dot8(hv1, w1, dot8(hv0, w0, acc1[g]))));
        }
      }
      att2_s[tid]        = acc1[0] + bda0;
      att2_s[256 + tid]  = acc1[1] + bda1;
      gate_s[tid]        = sigm(acc1[2] + bbe0);
      gate_s[256 + tid]  = sigm(acc1[3] + bbe1);
      #pragma unroll
      for (int g = 4; g < 10; ++g)
        gh[(g - 4) * 256 + tid] = acc1[g] + bhh6[g - 4];
    }
    __syncthreads();
    // ---- attention (all LDS-local) ----
    {
      bool act = t < lenB;
      int a0i = l * 8;
      #pragma unroll 1
      for (int i = 0; i < 13; ++i) {
        int s = w + 4 * i;
        if (s < S_) {
          f16x8 av = *(const f16x8*)&at[s * 512 + a0i];
          float p = 0.f;
          #pragma unroll
          for (int jx = 0; jx < 8; ++jx) {
            float v = (float)av[jx] + att2_s[a0i + jx];
            v = v > 0.f ? v : 0.f;
            p = fmaf(v, wfa[jx], p);
          }
          #pragma unroll
          for (int off = 32; off > 0; off >>= 1) p += __shfl_xor(p, off, 64);
          if (l == 0) att_s[s] = p + bfa0;
        }
      }
      __syncthreads();
      if (tid < 64) {
        float x = (tid < S_) ? att_s[tid] : -1e30f;
        float m = x;
        #pragma unroll
        for (int off = 32; off > 0; off >>= 1) m = fmaxf(m, __shfl_xor(m, off, 64));
        float e = (tid < S_) ? __expf(x - m) : 0.f;
        float su = e;
        #pragma unroll
        for (int off = 32; off > 0; off >>= 1) su += __shfl_xor(su, off, 64);
        if (tid < S_) alpha_s[tid] = e / su;
      }
      __syncthreads();
      if (tid < S_) {
        float al = alpha_s[tid];
        alphas[((size_t)b * T_ + t) * S_ + tid] = act ? scope_r * al : 0.f;
        scope_r = act ? scope_r * (1.f - al) : scope_r;
      }
      if (tid < 128) {
        int e0 = tid * 4;
        float s0 = 0.f, s1 = 0.f, s2 = 0.f, s3 = 0.f;
        #pragma unroll 7
        for (int s = 0; s < S_; ++s) {
          float al = alpha_s[s];
          f16x4 fv = *(const f16x4*)&fe[s * 512 + e0];
          s0 = fmaf(al, (float)fv[0], s0);
          s1 = fmaf(al, (float)fv[1], s1);
          s2 = fmaf(al, (float)fv[2], s2);
          s3 = fmaf(al, (float)fv[3], s3);
        }
        f16x4 o;
        o[0] = (f16)(gate_s[e0 + 0] * s0);
        o[1] = (f16)(gate_s[e0 + 1] * s1);
        o[2] = (f16)(gate_s[e0 + 2] * s2);
        o[3] = (f16)(gate_s[e0 + 3] * s3);
        *(f16x4*)&xg[e0] = o;
      }
    }
    __syncthreads();
    // ---- phase 2: rows of Wih_awe (1536) dot xg ----
    {
      float acc2[6];
      #pragma unroll
      for (int g = 0; g < 6; ++g) acc2[g] = 0.f;
      #pragma unroll 1
      for (int kt = 0; kt < 16; ++kt) {
        f16x8 xv0 = *(const f16x8*)&xg[kt * 32];
        f16x8 xv1 = *(const f16x8*)&xg[kt * 32 + 8];
        f16x8 xv2 = *(const f16x8*)&xg[kt * 32 + 16];
        f16x8 xv3 = *(const f16x8*)&xg[kt * 32 + 24];
        #pragma unroll
        for (int g = 0; g < 6; ++g) {
          const f16* wr = Wfull2 + (size_t)(g * 256 + tid) * 512 + kt * 32;
          f16x8 w0 = *(const f16x8*)wr;
          f16x8 w1 = *(const f16x8*)(wr + 8);
          f16x8 w2 = *(const f16x8*)(wr + 16);
          f16x8 w3 = *(const f16x8*)(wr + 24);
          acc2[g] = dot8(xv3, w3, dot8(xv2, w2, dot8(xv1, w1, dot8(xv0, w0, acc2[g]))));
        }
      }
      #pragma unroll
      for (int g = 0; g < 6; ++g)
        gix[g * 256 + tid] = acc2[g];
    }
    __syncthreads();
    // ---- pointwise GRU: j = tid and tid+256 ----
    {
      const float* gim = gi + (size_t)(t * 64 + b) * G3;
      bool act = t < lenB;
      #pragma unroll
      for (int q = 0; q < 2; ++q) {
        int j = q * 256 + tid;
        float r = sigm(gix[j] + gim[j] + gh[j]);
        float z = sigm(gix[512 + j] + gim[512 + j] + gh[512 + j]);
        float n = tanhf(gix[1024 + j] + gim[1024 + j] + r * gh[1024 + j]);
        float hold = (float)hx[j];
        float hn = (1.f - z) * n + z * hold;
        hx[j] = (f16)(act ? hn : hold);
        Hbuf[((size_t)b * T_ + t) * 512 + j] = (f16)hn;
      }
    }
    __syncthreads();
  }
}

// ---------------- Phase C: out = actmask * (Hbuf @ Wout.T + b_out), f16 MFMA ----------------
__global__ __launch_bounds__(256) void k_outgemm(
    const f16* __restrict__ A, const f16* __restrict__ Bw,
    const float* __restrict__ b_out, const float* __restrict__ actmask,
    float* __restrict__ out) {
  const int bid = blockIdx.x;
  const int swz = (bid & 7) * 500 + (bid >> 3);
  const int mb = (swz & 15) * 128;
  const int nb = (swz >> 4) * 128;
  GEMM16_CORE
  #pragma unroll
  for (int ni = 0; ni < 4; ++ni) {
    int n = nb + wc * 64 + ni * 16 + lm;
    float bo = b_out[n];
    #pragma unroll
    for (int mi = 0; mi < 4; ++mi) {
      int m0 = mb + wr * 64 + mi * 16 + (l >> 4) * 4;
      #pragma unroll
      for (int r = 0; r < 4; ++r) {
        int m = m0 + r;
        out[(size_t)m * V_ + n] = actmask[m] * (acc[mi][ni][r] + bo);
      }
    }
  }
}

extern "C" void kernel_launch(void* const* d_in, const int* in_sizes, int n_in,
                              void* d_out, int out_size, void* d_ws, size_t ws_size,
                              hipStream_t stream) {
  const float* feats  = (const float*)d_in[0];
  const int*   seq    = (const int*)d_in[1];
  const int*   length = (const int*)d_in[2];
  const float* emb    = (const float*)d_in[3];
  const float* W_ih   = (const float*)d_in[4];
  const float* b_ih   = (const float*)d_in[5];
  const float* W_hh   = (const float*)d_in[6];
  const float* b_hh   = (const float*)d_in[7];
  const float* W_out  = (const float*)d_in[8];
  const float* b_out  = (const float*)d_in[9];
  const float* W_init = (const float*)d_in[10];
  const float* b_init = (const float*)d_in[11];
  const float* W_beta = (const float*)d_in[12];
  const float* b_beta = (const float*)d_in[13];
  const float* W_ea   = (const float*)d_in[14];
  const float* b_ea   = (const float*)d_in[15];
  const float* W_da   = (const float*)d_in[16];
  const float* b_da   = (const float*)d_in[17];
  const float* W_fa   = (const float*)d_in[18];
  const float* b_fa   = (const float*)d_in[19];

  float* out    = (float*)d_out;
  float* alphas = out + (size_t)B_ * T_ * V_;

  // ---- workspace layout ----
  float* ws = (float*)d_ws;
  float* h0       = ws;              ws += B_ * D_;
  float* hmean    = ws;              ws += B_ * D_;
  float* actmask  = ws;              ws += B_ * T_;
  float* gi       = ws;              ws += (size_t)B_ * T_ * G3;
  f16* fp = (f16*)ws;
  f16* Woutb   = fp;  fp += (size_t)V_ * D_;
  f16* Hbuf    = fp;  fp += (size_t)B_ * T_ * D_;
  f16* Wfull1  = fp;  fp += (size_t)2560 * D_;
  f16* Wfull2  = fp;  fp += (size_t)G3 * D_;
  f16* Wp3     = fp;  fp += (size_t)G3 * D_;
  f16* Wea16   = fp;  fp += (size_t)D_ * D_;
  f16* xemb16  = fp;  fp += (size_t)B_ * T_ * D_;
  f16* feats16 = fp;  fp += (size_t)3200 * D_;   // padded to 25 m-tiles
  f16* att116  = fp;  fp += (size_t)B_ * S_ * D_;
  f16* h016    = fp;  fp += B_ * D_;

  // ---- Phase A ----
  k_prep<<<2048, 256, 0, stream>>>(W_out, Woutb, W_ea, Wea16, feats, feats16,
                                   emb, seq, length, xemb16, actmask, hmean,
                                   W_da, W_beta, W_hh, W_ih,
                                   Wfull1, Wfull2, Wp3);
  k_gemm_f32<<<dim3(8, 1), 256, 0, stream>>>(h0, h016, hmean, W_init, b_init, 512, 512, 512);
  k_gemm16f<<<dim3(4, 25), 256, 0, stream>>>(feats16, Wea16, b_ea, att116);
  k_gemm16g<<<dim3(12, 16), 256, 0, stream>>>(xemb16, Wp3, b_ih, gi);

  // ---- Phase B: batch-parallel zero-sync recurrence ----
  k_recur<<<B_, 256, 0, stream>>>(Wfull1, Wfull2, att116, feats16, gi,
      b_da, b_beta, b_hh, W_fa, b_fa, length, h016, alphas, Hbuf);

  // ---- Phase C: output projection ----
  k_outgemm<<<4000, 256, 0, stream>>>(Hbuf, Woutb, b_out, actmask, out);
}

// Round 18
// 910.292 us; speedup vs baseline: 4.8620x; 4.8620x over previous
//
#include <hip/hip_runtime.h>
#include <cstdint>
#include <cstddef>

#define B_   64
#define S_   49
#define T_   32
#define D_   512
#define V_   32000
#define G3   1536
#define NBLK 64

typedef float v4f   __attribute__((ext_vector_type(4)));
typedef int   i32x4 __attribute__((ext_vector_type(4)));
typedef _Float16 f16;
typedef _Float16 f16x8 __attribute__((ext_vector_type(8)));
typedef _Float16 f16x4 __attribute__((ext_vector_type(4)));

__device__ __forceinline__ float sigm(float x) { return 1.f / (1.f + __expf(-x)); }

// ---- agent-scope RELAXED atomics: coherent via IC, no L2 maintenance ----
__device__ __forceinline__ uint64_t ld_a64(const void* p) {
  return __hip_atomic_load((const uint64_t*)p, __ATOMIC_RELAXED, __HIP_MEMORY_SCOPE_AGENT);
}
__device__ __forceinline__ void st_a64(void* p, uint64_t v) {
  __hip_atomic_store((uint64_t*)p, v, __ATOMIC_RELAXED, __HIP_MEMORY_SCOPE_AGENT);
}
__device__ __forceinline__ uint32_t ld_a32(const void* p) {
  return __hip_atomic_load((const uint32_t*)p, __ATOMIC_RELAXED, __HIP_MEMORY_SCOPE_AGENT);
}
__device__ __forceinline__ void st_a32(void* p, uint32_t v) {
  __hip_atomic_store((uint32_t*)p, v, __ATOMIC_RELAXED, __HIP_MEMORY_SCOPE_AGENT);
}

__device__ __forceinline__ void cvt8(const float* __restrict__ in,
                                     f16* __restrict__ out) {
  float4 a = *(const float4*)in;
  float4 b = *(const float4*)(in + 4);
  f16x8 o;
  o[0] = (f16)a.x; o[1] = (f16)a.y; o[2] = (f16)a.z; o[3] = (f16)a.w;
  o[4] = (f16)b.x; o[5] = (f16)b.y; o[6] = (f16)b.z; o[7] = (f16)b.w;
  *(f16x8*)out = o;
}

// ---------------- merged prep kernel (one dispatch replaces 5) ----------------
// segments: Wout->f16 | Wea->f16 | feats->f16 | embed gather->f16 | hmean | actmask
__global__ __launch_bounds__(256) void k_prep(
    const float* __restrict__ Wout, f16* __restrict__ Woutb,
    const float* __restrict__ Wea, f16* __restrict__ Wea16,
    const float* __restrict__ feats, f16* __restrict__ feats16,
    const float* __restrict__ emb, const int* __restrict__ seq,
    const int* __restrict__ length,
    f16* __restrict__ xemb16, float* __restrict__ actmask,
    float* __restrict__ hmean) {
  const size_t N1 = (size_t)V_ * D_ / 8;
  const size_t N2 = N1 + (size_t)D_ * D_ / 8;
  const size_t N3 = N2 + (size_t)B_ * S_ * D_ / 8;
  const size_t N4 = N3 + (size_t)B_ * T_ * D_ / 8;
  const size_t N5 = N4 + (size_t)B_ * D_;
  const size_t N6 = N5 + (size_t)B_ * T_;
  for (size_t i = (size_t)blockIdx.x * 256 + threadIdx.x; i < N6;
       i += (size_t)gridDim.x * 256) {
    if (i < N1) {
      cvt8(Wout + i * 8, Woutb + i * 8);
    } else if (i < N2) {
      size_t j = i - N1;
      cvt8(Wea + j * 8, Wea16 + j * 8);
    } else if (i < N3) {
      size_t j = i - N2;
      cvt8(feats + j * 8, feats16 + j * 8);
    } else if (i < N4) {
      size_t j = i - N3;
      int m = (int)(j >> 6), c = (int)(j & 63);
      int t = m >> 6, b = m & 63;
      int idx = seq[b * T_ + t];
      cvt8(emb + (size_t)idx * D_ + c * 8, xemb16 + (size_t)m * D_ + c * 8);
    } else if (i < N5) {
      size_t j = i - N4;
      int b = (int)(j >> 9), e = (int)(j & 511);
      float s = 0.f;
      for (int si = 0; si < S_; ++si)
        s += feats[((size_t)b * S_ + si) * D_ + e];
      hmean[b * D_ + e] = s * (1.f / 49.f);
    } else {
      size_t j = i - N5;
      int b = (int)(j >> 5), t = (int)(j & 31);
      actmask[b * T_ + t] = (t < length[b]) ? 1.f : 0.f;
    }
  }
}

// ---------------- fp32 GEMM (h0 only): also emits f16 copy ----------------
__global__ __launch_bounds__(256) void k_gemm_f32(
    float* __restrict__ C, f16* __restrict__ C16,
    const float* __restrict__ X, const float* __restrict__ W,
    const float* __restrict__ bias, int N, int K, int ldw) {
  __shared__ __align__(16) float XsT[32][68];
  __shared__ __align__(16) float WsT[32][68];
  const int nbase = blockIdx.x * 64, mbase = blockIdx.y * 64;
  const int tid = threadIdx.x;
  const int lr = tid >> 2;
  const int lk = (tid & 3) * 8;
  const int ty = tid >> 4, tx = tid & 15;
  float acc[4][4] = {};
  for (int k0 = 0; k0 < K; k0 += 32) {
    {
      const float* xs = X + (size_t)(mbase + lr) * K + k0 + lk;
      const float* wsrc = W + (size_t)(nbase + lr) * ldw + k0 + lk;
      float4 x0 = *(const float4*)xs, x1 = *(const float4*)(xs + 4);
      float4 w0 = *(const float4*)wsrc, w1 = *(const float4*)(wsrc + 4);
      XsT[lk + 0][lr] = x0.x; XsT[lk + 1][lr] = x0.y; XsT[lk + 2][lr] = x0.z; XsT[lk + 3][lr] = x0.w;
      XsT[lk + 4][lr] = x1.x; XsT[lk + 5][lr] = x1.y; XsT[lk + 6][lr] = x1.z; XsT[lk + 7][lr] = x1.w;
      WsT[lk + 0][lr] = w0.x; WsT[lk + 1][lr] = w0.y; WsT[lk + 2][lr] = w0.z; WsT[lk + 3][lr] = w0.w;
      WsT[lk + 4][lr] = w1.x; WsT[lk + 5][lr] = w1.y; WsT[lk + 6][lr] = w1.z; WsT[lk + 7][lr] = w1.w;
    }
    __syncthreads();
    #pragma unroll
    for (int kk = 0; kk < 32; ++kk) {
      float4 a4 = *(const float4*)&XsT[kk][ty * 4];
      float4 w4 = *(const float4*)&WsT[kk][tx * 4];
      float av[4] = {a4.x, a4.y, a4.z, a4.w};
      float wv[4] = {w4.x, w4.y, w4.z, w4.w};
      #pragma unroll
      for (int i = 0; i < 4; ++i)
        #pragma unroll
        for (int j = 0; j < 4; ++j)
          acc[i][j] = fmaf(av[i], wv[j], acc[i][j]);
    }
    __syncthreads();
  }
  #pragma unroll
  for (int i = 0; i < 4; ++i) {
    int m = mbase + ty * 4 + i;
    int n = nbase + tx * 4;
    float4 o;
    o.x = acc[i][0] + bias[n + 0];
    o.y = acc[i][1] + bias[n + 1];
    o.z = acc[i][2] + bias[n + 2];
    o.w = acc[i][3] + bias[n + 3];
    *(float4*)&C[(size_t)m * N + n] = o;
    if (C16) {
      f16x4 h;
      h[0] = (f16)o.x; h[1] = (f16)o.y; h[2] = (f16)o.z; h[3] = (f16)o.w;
      *(f16x4*)&C16[(size_t)m * N + n] = h;
    }
  }
}

// ---------------- f16 MFMA GEMM core (argument-free macro; epilogue follows) --
#define GEMM16_CORE                                                            \
  __shared__ __align__(16) f16 As[128 * 32];                                   \
  __shared__ __align__(16) f16 Bs[128 * 32];                                   \
  const int tid = threadIdx.x;                                                 \
  const int l = tid & 63, w = tid >> 6;                                        \
  const int wr = w >> 1, wc = w & 1;                                           \
  const int lm = l & 15;                                                       \
  const int kc = l >> 4;                                                       \
  const int rchunk = (kc ^ ((lm >> 1) & 3)) * 8;                               \
  v4f acc[4][4];                                                               \
  _Pragma("unroll")                                                            \
  for (int mi = 0; mi < 4; ++mi)                                               \
    _Pragma("unroll")                                                          \
    for (int ni = 0; ni < 4; ++ni)                                             \
      acc[mi][ni] = (v4f){0.f, 0.f, 0.f, 0.f};                                 \
  i32x4 ra[2], rb[2];                                                          \
  auto LD = [&](int k0) {                                                      \
    _Pragma("unroll")                                                          \
    for (int i = 0; i < 2; ++i) {                                              \
      int ch = i * 256 + tid;                                                  \
      int row = ch >> 2, cq = ch & 3;                                          \
      ra[i] = *(const i32x4*)&A[(size_t)(mb + row) * 512 + k0 + cq * 8];       \
      rb[i] = *(const i32x4*)&Bw[(size_t)(nb + row) * 512 + k0 + cq * 8];      \
    }                                                                          \
  };                                                                           \
  LD(0);                                                                       \
  for (int k0 = 0; k0 < 512; k0 += 32) {                                       \
    _Pragma("unroll")                                                          \
    for (int i = 0; i < 2; ++i) {                                              \
      int ch = i * 256 + tid;                                                  \
      int row = ch >> 2, cq = ch & 3;                                          \
      int sc = (cq ^ ((row >> 1) & 3)) * 8;                                    \
      *(i32x4*)&As[row * 32 + sc] = ra[i];                                     \
      *(i32x4*)&Bs[row * 32 + sc] = rb[i];                                     \
    }                                                                          \
    __syncthreads();                                                           \
    if (k0 < 480) LD(k0 + 32);                                                 \
    f16x8 af[4], bf[4];                                                        \
    _Pragma("unroll")                                                          \
    for (int mi = 0; mi < 4; ++mi)                                             \
      af[mi] = *(const f16x8*)&As[(wr * 64 + mi * 16 + lm) * 32 + rchunk];     \
    _Pragma("unroll")                                                          \
    for (int ni = 0; ni < 4; ++ni)                                             \
      bf[ni] = *(const f16x8*)&Bs[(wc * 64 + ni * 16 + lm) * 32 + rchunk];     \
    _Pragma("unroll")                                                          \
    for (int mi = 0; mi < 4; ++mi)                                             \
      _Pragma("unroll")                                                        \
      for (int ni = 0; ni < 4; ++ni)                                           \
        acc[mi][ni] = __builtin_amdgcn_mfma_f32_16x16x32_f16(af[mi], bf[ni], acc[mi][ni], 0, 0, 0); \
    __syncthreads();                                                           \
  }

// att116 = feats16 @ W_ea16.T + b_ea -> f16 out, M guarded at 3136
__global__ __launch_bounds__(256) void k_gemm16f(
    const f16* __restrict__ A, const f16* __restrict__ Bw,
    const float* __restrict__ bias, f16* __restrict__ out) {
  const int nb = blockIdx.x * 128, mb = blockIdx.y * 128;
  GEMM16_CORE
  #pragma unroll
  for (int ni = 0; ni < 4; ++ni) {
    int n = nb + wc * 64 + ni * 16 + lm;
    float bo = bias[n];
    #pragma unroll
    for (int mi = 0; mi < 4; ++mi) {
      int m0 = mb + wr * 64 + mi * 16 + (l >> 4) * 4;
      #pragma unroll
      for (int r = 0; r < 4; ++r) {
        int m = m0 + r;
        if (m < B_ * S_) out[(size_t)m * 512 + n] = (f16)(acc[mi][ni][r] + bo);
      }
    }
  }
}

// gi GEMM: xemb16 @ Wp3.T + b_ih, scatter-stored straight into gi_pack layout
__global__ __launch_bounds__(256) void k_gemm16g(
    const f16* __restrict__ A, const f16* __restrict__ Bw,
    const float* __restrict__ bias, float* __restrict__ out) {
  const int nb = blockIdx.x * 128, mb = blockIdx.y * 128;
  GEMM16_CORE
  #pragma unroll
  for (int ni = 0; ni < 4; ++ni) {
    int n = nb + wc * 64 + ni * 16 + lm;
    float bo = bias[n];
    int gate = n >> 9, rem = n & 511;
    int Kb = rem >> 3, jl = rem & 7;
    #pragma unroll
    for (int mi = 0; mi < 4; ++mi) {
      int m0 = mb + wr * 64 + mi * 16 + (l >> 4) * 4;
      int t = m0 >> 6, b0q = m0 & 63;
      float* dst = out + (((size_t)t * 64 + Kb) * 32 + gate * 8 + jl) * 64 + b0q;
      #pragma unroll
      for (int r = 0; r < 4; ++r)
        dst[r] = acc[mi][ni][r] + bo;
    }
  }
}

// ---------------- pack kernels ----------------
__global__ __launch_bounds__(256) void k_packW(
    const float* __restrict__ Wda, const float* __restrict__ Wbe,
    const float* __restrict__ Whh, const float* __restrict__ Wih,
    f16* __restrict__ Wp1, f16* __restrict__ Wp2, f16* __restrict__ Wp3) {
  int K = blockIdx.x, tid = threadIdx.x;
  for (int idx = tid; idx < 40 * 512; idx += 256) {
    int r = idx >> 9, e = idx & 511;
    float v;
    if (r < 8)       v = Wda[(size_t)(8 * K + r) * D_ + e];
    else if (r < 16) v = Wbe[(size_t)(8 * K + r - 8) * D_ + e];
    else if (r < 24) v = Whh[(size_t)(8 * K + r - 16) * D_ + e];
    else if (r < 32) v = Whh[(size_t)(512 + 8 * K + r - 24) * D_ + e];
    else             v = Whh[(size_t)(1024 + 8 * K + r - 32) * D_ + e];
    Wp1[(size_t)K * 20480 + idx] = (f16)v;
  }
  for (int idx = tid; idx < 24 * 512; idx += 256) {
    int r = idx >> 9, e = idx & 511;
    int g = r >> 3, jj = r & 7;
    float v = Wih[(size_t)(g * 512 + 8 * K + jj) * 1024 + 512 + e];
    Wp2[(size_t)K * 12288 + idx] = (f16)v;
  }
  for (int idx = tid; idx < 24 * 512; idx += 256) {
    int rl = idx >> 9, e = idx & 511;
    int r = K * 24 + rl;
    Wp3[(size_t)r * 512 + e] = (f16)Wih[(size_t)r * 1024 + e];
  }
}

// -------- padded-flag sync: tight poll, single wave --------
__device__ __forceinline__ void wait_flags64(const int* __restrict__ flags,
                                             int target, int tid) {
  if (tid < 64) {
    while (!__all((int)ld_a32(flags + tid * 16) >= target)) {}
  }
  __syncthreads();
}

__device__ __forceinline__ void set_flag(int* slot, int val, int tid) {
  __syncthreads();   // vmcnt(0) before s_barrier: prior data stores complete
  if (tid == 0) st_a32(slot, (uint32_t)val);
}

// stage 64KB state: 16-deep coalesced 16B IC loads, one drain
__device__ __forceinline__ void stage_fast(const f16* __restrict__ src,
                                           uint4* __restrict__ hs, int tid) {
  const i32x4* s = (const i32x4*)src;
  i32x4 v[16];
  #pragma unroll
  for (int i = 0; i < 16; ++i) {
    asm volatile("global_load_dwordx4 %0, %1, off sc0 sc1"
                 : "=v"(v[i]) : "v"(s + i * 256 + tid));
  }
  asm volatile("s_waitcnt vmcnt(0)" ::: "memory");
  __builtin_amdgcn_sched_barrier(0);
  #pragma unroll
  for (int i = 0; i < 16; ++i) {
    int g = i * 256 + tid;
    int b = g >> 6, c = g & 63;
    *(i32x4*)&hs[b * 64 + (c ^ (b & 7))] = v[i];
  }
}

// ---------------- persistent recurrence: 64 blocks, block K owns j in [8K,8K+8) ----------------
// (R12-proven: 670us. att116 preload before waitA; MV1b split around the waits.)
__global__ __launch_bounds__(256, 1) void k_recur(
    const f16* __restrict__ Wp1, const f16* __restrict__ Wp2,
    const f16* __restrict__ att116, const f16* __restrict__ feats16,
    const float* __restrict__ gi_pack,
    const float* __restrict__ b_da, const float* __restrict__ b_beta,
    const float* __restrict__ b_hh,
    const float* __restrict__ W_fa, const float* __restrict__ b_fa,
    const int* __restrict__ length,
    f16* __restrict__ h16, f16* __restrict__ xg16,
    float* __restrict__ att2g,
    float* __restrict__ alphas, f16* __restrict__ Hbuf,
    int* __restrict__ flags) {
  __shared__ __align__(16) uint4 lds_all[8704];
  __shared__ float gh_lds[24 * 72];
  __shared__ float gix_lds[24 * 72];
  __shared__ float att2_s[512];
  __shared__ float gate_s[512];
  __shared__ float att_s[64];
  __shared__ float alpha_s[64];
  uint4* hs = lds_all;
  uint4* W1 = lds_all + 4096;
  uint4* W2 = lds_all + 6656;
  float* attp = (float*)(lds_all + 8192);

  const int K = blockIdx.x, tid = threadIdx.x;
  const int w = tid >> 6, l = tid & 63;
  const int lm = l & 15, c4 = l >> 4;
  const int bq = tid & 63, jg = tid >> 6;
  const int jj0 = 2 * jg, jj1 = 2 * jg + 1;
  int* flagA = flags;
  int* flagB = flags + 1024;
  int* flagC = flags + 2048;

  {
    const uint4* s1 = (const uint4*)(Wp1 + (size_t)K * 20480);
    const uint4* s2 = (const uint4*)(Wp2 + (size_t)K * 12288);
    #pragma unroll
    for (int i = 0; i < 10; ++i) {
      int g = i * 256 + tid;
      int s = g >> 6, c = g & 63;
      W1[s * 64 + (c ^ (s & 7))] = s1[g];
    }
    #pragma unroll
    for (int i = 0; i < 6; ++i) {
      int g = i * 256 + tid;
      int s = g >> 6, c = g & 63;
      W2[s * 64 + (c ^ (s & 7))] = s2[g];
    }
  }
  const int lenB = length[K];
  const float bfa0 = b_fa[0];
  const int lb = length[bq];
  const float bhr0 = b_hh[8 * K + jj0],        bhr1 = b_hh[8 * K + jj1];
  const float bhz0 = b_hh[512 + 8 * K + jj0],  bhz1 = b_hh[512 + 8 * K + jj1];
  const float bhn0 = b_hh[1024 + 8 * K + jj0], bhn1 = b_hh[1024 + 8 * K + jj1];
  float wfa[8];
  {
    int a0i = l * 8;
    #pragma unroll
    for (int jx = 0; jx < 8; ++jx) wfa[jx] = W_fa[a0i + jx];
  }
  const float bda0 = b_da[2 * tid], bda1 = b_da[2 * tid + 1];
  const float bbe0 = b_beta[2 * tid], bbe1 = b_beta[2 * tid + 1];
  float scope_r = 1.f;
  __syncthreads();

  for (int t = 0; t < T_; ++t) {
    if (t) wait_flags64(flagC, t, tid);
    stage_fast(h16, hs, tid);
    __syncthreads();
    float hold0, hold1;
    {
      f16x8 hv = __builtin_bit_cast(f16x8, hs[bq * 64 + (K ^ (bq & 7))]);
      hold0 = (float)hv[jj0]; hold1 = (float)hv[jj1];
    }
    // ---- MV1a: att2/gate rows (W1 rows 0-15) -> attp ----
    {
      v4f a0 = {0.f, 0.f, 0.f, 0.f};
      int bb = w * 16 + lm;
      #pragma unroll
      for (int kt = 0; kt < 16; ++kt) {
        int ca = kt * 4 + c4;
        f16x8 av = __builtin_bit_cast(f16x8, hs[bb * 64 + (ca ^ (bb & 7))]);
        f16x8 b0 = __builtin_bit_cast(f16x8, W1[lm * 64 + (ca ^ (lm & 7))]);
        a0 = __builtin_amdgcn_mfma_f32_16x16x32_f16(av, b0, a0, 0, 0, 0);
      }
      #pragma unroll
      for (int r = 0; r < 4; ++r)
        attp[(w * 16 + c4 * 4 + r) * 16 + lm] = a0[r];
    }
    __syncthreads();
    #pragma unroll
    for (int q = 0; q < 2; ++q) {
      int pp = tid * 2 + q;
      int bat = pp >> 3, pi = pp & 7;
      float2 f2;
      f2.x = attp[bat * 16 + 2 * pi];
      f2.y = attp[bat * 16 + 2 * pi + 1];
      size_t idx = (size_t)bat * 512 +
                   ((pi < 4) ? (4 * K + pi) : (256 + 4 * K + (pi - 4)));
      st_a64((uint64_t*)att2g + idx, __builtin_bit_cast(uint64_t, f2));
    }
    set_flag(flagA + K * 16, t + 1, tid);
    // ---- preload att116 score operands (flag-independent) ----
    i32x4 attv[13];
    #pragma unroll
    for (int i = 0; i < 13; ++i) {
      int s = w + 4 * i;
      if (s < S_)
        attv[i] = *(const i32x4*)(att116 + ((size_t)K * S_ + s) * D_ + l * 8);
    }
    // ---- MV1b-rz (overlaps waitA) ----
    {
      v4f a1 = {0.f, 0.f, 0.f, 0.f};
      int bb = w * 16 + lm;
      #pragma unroll
      for (int kt = 0; kt < 16; ++kt) {
        int ca = kt * 4 + c4;
        f16x8 av = __builtin_bit_cast(f16x8, hs[bb * 64 + (ca ^ (bb & 7))]);
        f16x8 b1 = __builtin_bit_cast(f16x8, W1[(16 + lm) * 64 + (ca ^ ((16 + lm) & 7))]);
        a1 = __builtin_amdgcn_mfma_f32_16x16x32_f16(av, b1, a1, 0, 0, 0);
      }
      #pragma unroll
      for (int r = 0; r < 4; ++r)
        gh_lds[lm * 72 + (w * 16 + c4 * 4 + r)] = a1[r];
    }
    wait_flags64(flagA, t + 1, tid);
    // ---- attention for batch K ----
    {
      bool act = t < lenB;
      const uint64_t* arow2 = (const uint64_t*)att2g + (size_t)K * 512;
      {
        float2 f = __builtin_bit_cast(float2, ld_a64(arow2 + tid));
        att2_s[2 * tid]     = f.x + bda0;
        att2_s[2 * tid + 1] = f.y + bda1;
        float2 g = __builtin_bit_cast(float2, ld_a64(arow2 + tid + 256));
        gate_s[2 * tid]     = sigm(g.x + bbe0);
        gate_s[2 * tid + 1] = sigm(g.y + bbe1);
      }
      __syncthreads();
      int a0i = l * 8;
      #pragma unroll
      for (int i = 0; i < 13; ++i) {
        int s = w + 4 * i;
        if (s < S_) {
          f16x8 av = __builtin_bit_cast(f16x8, attv[i]);
          float p = 0.f;
          #pragma unroll
          for (int jx = 0; jx < 8; ++jx) {
            float v = (float)av[jx] + att2_s[a0i + jx];
            v = v > 0.f ? v : 0.f;
            p = fmaf(v, wfa[jx], p);
          }
          #pragma unroll
          for (int off = 32; off > 0; off >>= 1) p += __shfl_xor(p, off, 64);
          if (l == 0) att_s[s] = p + bfa0;
        }
      }
      __syncthreads();
      if (tid < 64) {
        float x = (tid < S_) ? att_s[tid] : -1e30f;
        float m = x;
        #pragma unroll
        for (int off = 32; off > 0; off >>= 1) m = fmaxf(m, __shfl_xor(m, off, 64));
        float e = (tid < S_) ? __expf(x - m) : 0.f;
        float su = e;
        #pragma unroll
        for (int off = 32; off > 0; off >>= 1) su += __shfl_xor(su, off, 64);
        if (tid < S_) alpha_s[tid] = e / su;
      }
      __syncthreads();
      if (tid < S_) {
        float al = alpha_s[tid];
        alphas[((size_t)K * T_ + t) * S_ + tid] = act ? scope_r * al : 0.f;
        scope_r = act ? scope_r * (1.f - al) : scope_r;
      }
      if (tid < 128) {
        int e0 = tid * 4;
        float s0 = 0.f, s1 = 0.f, s2 = 0.f, s3 = 0.f;
        #pragma unroll 7
        for (int s = 0; s < S_; ++s) {
          float al = alpha_s[s];
          f16x4 fv = *(const f16x4*)(feats16 + ((size_t)K * S_ + s) * D_ + e0);
          s0 = fmaf(al, (float)fv[0], s0);
          s1 = fmaf(al, (float)fv[1], s1);
          s2 = fmaf(al, (float)fv[2], s2);
          s3 = fmaf(al, (float)fv[3], s3);
        }
        f16x4 o;
        o[0] = (f16)(gate_s[e0 + 0] * s0);
        o[1] = (f16)(gate_s[e0 + 1] * s1);
        o[2] = (f16)(gate_s[e0 + 2] * s2);
        o[3] = (f16)(gate_s[e0 + 3] * s3);
        st_a64((uint64_t*)xg16 + (size_t)K * 128 + tid,
               __builtin_bit_cast(uint64_t, o));
      }
    }
    set_flag(flagB + K * 16, t + 1, tid);
    // ---- MV1b-n (overlaps waitB; hs still h) ----
    {
      v4f a2 = {0.f, 0.f, 0.f, 0.f};
      int bb = w * 16 + lm;
      #pragma unroll
      for (int kt = 0; kt < 16; ++kt) {
        int ca = kt * 4 + c4;
        f16x8 av = __builtin_bit_cast(f16x8, hs[bb * 64 + (ca ^ (bb & 7))]);
        f16x8 b2 = __builtin_bit_cast(f16x8, W1[(32 + lm) * 64 + (ca ^ ((32 + lm) & 7))]);
        a2 = __builtin_amdgcn_mfma_f32_16x16x32_f16(av, b2, a2, 0, 0, 0);
      }
      #pragma unroll
      for (int r = 0; r < 4; ++r)
        if (lm < 8) gh_lds[(16 + lm) * 72 + (w * 16 + c4 * 4 + r)] = a2[r];
    }
    wait_flags64(flagB, t + 1, tid);
    stage_fast(xg16, hs, tid);
    __syncthreads();
    // ---- MV2 ----
    {
      v4f c0 = {0.f,0.f,0.f,0.f}, c1 = {0.f,0.f,0.f,0.f};
      int bb = w * 16 + lm;
      #pragma unroll
      for (int kt = 0; kt < 16; ++kt) {
        int ca = kt * 4 + c4;
        f16x8 av = __builtin_bit_cast(f16x8, hs[bb * 64 + (ca ^ (bb & 7))]);
        f16x8 b0 = __builtin_bit_cast(f16x8, W2[lm * 64 + (ca ^ (lm & 7))]);
        f16x8 b1 = __builtin_bit_cast(f16x8, W2[(16 + lm) * 64 + (ca ^ ((16 + lm) & 7))]);
        c0 = __builtin_amdgcn_mfma_f32_16x16x32_f16(av, b0, c0, 0, 0, 0);
        c1 = __builtin_amdgcn_mfma_f32_16x16x32_f16(av, b1, c1, 0, 0, 0);
      }
      #pragma unroll
      for (int r = 0; r < 4; ++r) {
        int bat = w * 16 + c4 * 4 + r;
        gix_lds[lm * 72 + bat] = c0[r];
        if (lm < 8) gix_lds[(16 + lm) * 72 + bat] = c1[r];
      }
    }
    __syncthreads();
    // ---- pointwise GRU ----
    {
      const float* gp = gi_pack + (size_t)(t * 64 + K) * 2048;
      float r0 = sigm(gix_lds[jj0 * 72 + bq] + gp[jj0 * 64 + bq] + gh_lds[jj0 * 72 + bq] + bhr0);
      float r1 = sigm(gix_lds[jj1 * 72 + bq] + gp[jj1 * 64 + bq] + gh_lds[jj1 * 72 + bq] + bhr1);
      float z0 = sigm(gix_lds[(8 + jj0) * 72 + bq] + gp[(8 + jj0) * 64 + bq] + gh_lds[(8 + jj0) * 72 + bq] + bhz0);
      float z1 = sigm(gix_lds[(8 + jj1) * 72 + bq] + gp[(8 + jj1) * 64 + bq] + gh_lds[(8 + jj1) * 72 + bq] + bhz1);
      float n0 = tanhf(gix_lds[(16 + jj0) * 72 + bq] + gp[(16 + jj0) * 64 + bq] + r0 * (gh_lds[(16 + jj0) * 72 + bq] + bhn0));
      float n1 = tanhf(gix_lds[(16 + jj1) * 72 + bq] + gp[(16 + jj1) * 64 + bq] + r1 * (gh_lds[(16 + jj1) * 72 + bq] + bhn1));
      float hn0 = (1.f - z0) * n0 + z0 * hold0;
      float hn1 = (1.f - z1) * n1 + z1 * hold1;
      bool act = t < lb;
      unsigned short u0 = __builtin_bit_cast(unsigned short, (f16)(act ? hn0 : hold0));
      unsigned short u1 = __builtin_bit_cast(unsigned short, (f16)(act ? hn1 : hold1));
      st_a32((uint32_t*)h16 + bq * 256 + 4 * K + jg,
             (uint32_t)u0 | ((uint32_t)u1 << 16));
      unsigned short p0 = __builtin_bit_cast(unsigned short, (f16)hn0);
      unsigned short p1 = __builtin_bit_cast(unsigned short, (f16)hn1);
      ((uint32_t*)Hbuf)[((size_t)bq * T_ + t) * 256 + 4 * K + jg] =
          (uint32_t)p0 | ((uint32_t)p1 << 16);
    }
    set_flag(flagC + K * 16, t + 1, tid);
  }
}

// ---------------- Phase C: out = actmask * (Hbuf @ Wout.T + b_out), f16 MFMA ----------------
__global__ __launch_bounds__(256) void k_outgemm(
    const f16* __restrict__ A, const f16* __restrict__ Bw,
    const float* __restrict__ b_out, const float* __restrict__ actmask,
    float* __restrict__ out) {
  const int bid = blockIdx.x;
  const int swz = (bid & 7) * 500 + (bid >> 3);
  const int mb = (swz & 15) * 128;
  const int nb = (swz >> 4) * 128;
  GEMM16_CORE
  #pragma unroll
  for (int ni = 0; ni < 4; ++ni) {
    int n = nb + wc * 64 + ni * 16 + lm;
    float bo = b_out[n];
    #pragma unroll
    for (int mi = 0; mi < 4; ++mi) {
      int m0 = mb + wr * 64 + mi * 16 + (l >> 4) * 4;
      #pragma unroll
      for (int r = 0; r < 4; ++r) {
        int m = m0 + r;
        out[(size_t)m * V_ + n] = actmask[m] * (acc[mi][ni][r] + bo);
      }
    }
  }
}

extern "C" void kernel_launch(void* const* d_in, const int* in_sizes, int n_in,
                              void* d_out, int out_size, void* d_ws, size_t ws_size,
                              hipStream_t stream) {
  const float* feats  = (const float*)d_in[0];
  const int*   seq    = (const int*)d_in[1];
  const int*   length = (const int*)d_in[2];
  const float* emb    = (const float*)d_in[3];
  const float* W_ih   = (const float*)d_in[4];
  const float* b_ih   = (const float*)d_in[5];
  const float* W_hh   = (const float*)d_in[6];
  const float* b_hh   = (const float*)d_in[7];
  const float* W_out  = (const float*)d_in[8];
  const float* b_out  = (const float*)d_in[9];
  const float* W_init = (const float*)d_in[10];
  const float* b_init = (const float*)d_in[11];
  const float* W_beta = (const float*)d_in[12];
  const float* b_beta = (const float*)d_in[13];
  const float* W_ea   = (const float*)d_in[14];
  const float* b_ea   = (const float*)d_in[15];
  const float* W_da   = (const float*)d_in[16];
  const float* b_da   = (const float*)d_in[17];
  const float* W_fa   = (const float*)d_in[18];
  const float* b_fa   = (const float*)d_in[19];

  float* out    = (float*)d_out;
  float* alphas = out + (size_t)B_ * T_ * V_;

  // ---- workspace layout ----
  float* ws = (float*)d_ws;
  int*   flags    = (int*)ws;        ws += 4096;  // 3 x 64 flags, 64B stride
  float* h0       = ws;              ws += B_ * D_;
  float* hmean    = ws;              ws += B_ * D_;
  float* actmask  = ws;              ws += B_ * T_;
  float* att2g    = ws;              ws += B_ * 1024;
  float* gi_pack  = ws;              ws += (size_t)T_ * 64 * 32 * 64;
  f16* fp = (f16*)ws;
  f16* Woutb   = fp;  fp += (size_t)V_ * D_;
  f16* Hbuf    = fp;  fp += (size_t)B_ * T_ * D_;
  f16* Wp1     = fp;  fp += (size_t)64 * 20480;
  f16* Wp2     = fp;  fp += (size_t)64 * 12288;
  f16* Wp3     = fp;  fp += (size_t)G3 * D_;
  f16* Wea16   = fp;  fp += (size_t)D_ * D_;
  f16* xemb16  = fp;  fp += (size_t)B_ * T_ * D_;
  f16* feats16 = fp;  fp += (size_t)3200 * D_;   // padded to 25 m-tiles
  f16* att116  = fp;  fp += (size_t)B_ * S_ * D_;
  f16* h16     = fp;  fp += B_ * D_;
  f16* xg16    = fp;  fp += B_ * D_;

  hipMemsetAsync(flags, 0, 16384, stream);

  // ---- Phase A (merged): prep -> packW -> h0 GEMM -> att1 GEMM -> gi GEMM ----
  k_prep<<<2048, 256, 0, stream>>>(W_out, Woutb, W_ea, Wea16, feats, feats16,
                                   emb, seq, length, xemb16, actmask, hmean);
  k_packW<<<64, 256, 0, stream>>>(W_da, W_beta, W_hh, W_ih, Wp1, Wp2, Wp3);
  k_gemm_f32<<<dim3(8, 1), 256, 0, stream>>>(h0, h16, hmean, W_init, b_init, 512, 512, 512);
  k_gemm16f<<<dim3(4, 25), 256, 0, stream>>>(feats16, Wea16, b_ea, att116);
  k_gemm16g<<<dim3(12, 16), 256, 0, stream>>>(xemb16, Wp3, b_ih, gi_pack);

  // ---- Phase B: persistent recurrence (split, R12-proven) ----
  k_recur<<<NBLK, 256, 0, stream>>>(Wp1, Wp2, att116, feats16, gi_pack,
      b_da, b_beta, b_hh, W_fa, b_fa, length,
      h16, xg16, att2g, alphas, Hbuf, flags);

  // ---- Phase C: output projection ----
  k_outgemm<<<4000, 256, 0, stream>>>(Hbuf, Woutb, b_out, actmask, out);
}